// Round 6
// baseline (338.729 us; speedup 1.0000x reference)
//
#include <hip/hip_runtime.h>

typedef _Float16 half8 __attribute__((ext_vector_type(8)));
typedef _Float16 half4 __attribute__((ext_vector_type(4)));
typedef float f32x4 __attribute__((ext_vector_type(4)));

#define T_STEPS 256
#define NB      8            // batches per block (8 -> 2 co-resident blocks/CU)
#define NBLOCKS (4096/NB)    // 512 blocks
#define LOG2E   1.4426950408889634f

// merged activation buffer stride (f16 units): cols 0..63 = h1, 64..127 = h2.
// 136 = 8*17 -> b128 reads: chunk slot (17*ln+lb)%8 = (ln+lb)%8 uniform;
// b64 writes: (68*ln+8*wq+2*lb)%32 uniform -> no bank conflicts.
#define SH 136

__device__ __forceinline__ half8 cvt8s(const float* __restrict__ p, float s) {
    half8 r;
    #pragma unroll
    for (int j = 0; j < 8; ++j) r[j] = (_Float16)(p[j] * s);
    return r;
}

// LDS-only barrier: does NOT drain vmcnt, so global x prefetch stays in flight.
__device__ __forceinline__ void sync_lds() {
    asm volatile("s_waitcnt lgkmcnt(0)" ::: "memory");
    __builtin_amdgcn_s_barrier();
}

__global__ __launch_bounds__(512, 1)
void lstm_v6(const float* __restrict__ x,
             const float* __restrict__ Wih0, const float* __restrict__ Whh0,
             const float* __restrict__ bih0, const float* __restrict__ bhh0,
             const float* __restrict__ Wih1, const float* __restrict__ Whh1,
             const float* __restrict__ bih1, const float* __restrict__ bhh1,
             const float* __restrict__ Wout, const float* __restrict__ bout,
             float* __restrict__ out)
{
    __shared__ _Float16 Hb[2][16][SH];

    const int tid  = threadIdx.x;
    const int w    = tid >> 6;
    const bool isL1 = (w < 4);          // waves 0-3: layer 1; waves 4-7: layer 2
    const int wq   = w & 3;
    const int l    = tid & 63;
    const int ln   = l & 15;            // weight row (A) / batch col (B)
    const int lb   = l >> 4;            // k sub-block / C-row group
    const int ub   = 16 * wq + 4 * lb;  // first unit this lane's acc covers
    const int gb0  = blockIdx.x * NB;

    // ---- weight A-fragments, register-resident, sign/scale pre-folded ----
    // gate q scale: i,f,o -> -log2e (exp2(acc) = e^{-raw}); g -> +2*log2e.
    half8 wa[4][4];   // L1 uses [q][0..1] (h1 part), L2 uses [q][0..3]
    half8 wax[4];     // L1 only: x part (K=32)
    f32x4 bv[4];
    if (isL1) {
        #pragma unroll
        for (int q = 0; q < 4; ++q) {
            const float s = (q == 2) ? 2.f * LOG2E : -LOG2E;
            const int g = 64 * q + 16 * wq + ln;
            wax[q] = cvt8s(Wih0 + g * 32 + 8 * lb, s);
            #pragma unroll
            for (int ks = 0; ks < 2; ++ks)
                wa[q][ks] = cvt8s(Whh0 + g * 64 + 32 * ks + 8 * lb, s);
            #pragma unroll
            for (int jj = 0; jj < 4; ++jj) {
                const int gj = 64 * q + ub + jj;
                bv[q][jj] = (bih0[gj] + bhh0[gj]) * s;
            }
        }
    } else {
        #pragma unroll
        for (int q = 0; q < 4; ++q) {
            const float s = (q == 2) ? 2.f * LOG2E : -LOG2E;
            const int g = 64 * q + 16 * wq + ln;
            #pragma unroll
            for (int ks = 0; ks < 4; ++ks) {
                const int c0 = 32 * ks + 8 * lb;
                const float* p = (c0 < 64) ? (Wih1 + g * 64 + c0)
                                           : (Whh1 + g * 64 + (c0 - 64));
                wa[q][ks] = cvt8s(p, s);
            }
            #pragma unroll
            for (int jj = 0; jj < 4; ++jj) {
                const int gj = 64 * q + ub + jj;
                bv[q][jj] = (bih1[gj] + bhh1[gj]) * s;
            }
        }
    }

    float cst[4] = {0.f, 0.f, 0.f, 0.f};

    // ---- zero LDS (h1(-1)=h2(-1)=h2(-2)=0) ----
    {
        unsigned int* z = (unsigned int*)Hb;
        for (int i = tid; i < (int)(sizeof(Hb) / 4); i += 512) z[i] = 0u;
    }

    // ---- L1 x pipeline: lane owns x[batch gb0+(ln&7)][t][8lb..8lb+7]
    //      (ln 8..15 duplicate 0..7 -> no OOB, loads broadcast from cache) ----
    const float* xb = x + (long)(gb0 + (ln & (NB - 1))) * T_STEPS * 32 + 8 * lb;
    f32x4 xr0 = {0.f,0.f,0.f,0.f}, xr1 = {0.f,0.f,0.f,0.f};
    f32x4 gxA[4], gxB[4];
    if (isL1) {
        // gx(0) = bias + W_x @ x(0)
        xr0 = *(const f32x4*)(xb);
        xr1 = *(const f32x4*)(xb + 4);
        half8 xf;
        #pragma unroll
        for (int j = 0; j < 4; ++j) { xf[j] = (_Float16)xr0[j]; xf[4+j] = (_Float16)xr1[j]; }
        #pragma unroll
        for (int q = 0; q < 4; ++q) {
            gxA[q] = bv[q];
            gxA[q] = __builtin_amdgcn_mfma_f32_16x16x32_f16(wax[q], xf, gxA[q], 0, 0, 0);
        }
        xr0 = *(const f32x4*)(xb + 32);      // x(1)
        xr1 = *(const f32x4*)(xb + 36);
    }
    sync_lds();

// LSTM cell update, weights pre-scaled: ei=e^{-i}, ef=e^{-f}, Eg=e^{2g}, eo=e^{-o}
// c' = [c*(1+ei)(1+Eg) + (Eg-1)(1+ef)] / ((1+ei)(1+Eg)(1+ef))
// h  = (Ec-1) / ((1+eo)(1+Ec)),  Ec = e^{2c'}
#define ACT1(A, JJ)                                                            \
    {                                                                          \
        const float ei = __builtin_amdgcn_exp2f(A[0][JJ]);                     \
        const float ef = __builtin_amdgcn_exp2f(A[1][JJ]);                     \
        const float Eg = __builtin_amdgcn_exp2f(A[2][JJ]);                     \
        const float eo = __builtin_amdgcn_exp2f(A[3][JJ]);                     \
        const float ti = 1.f + ei, tf = 1.f + ef, tg = 1.f + Eg;               \
        const float pig = ti * tg;                                             \
        const float num = fmaf(Eg - 1.f, tf, cst[JJ] * pig);                   \
        const float c   = num * __builtin_amdgcn_rcpf(pig * tf);               \
        cst[JJ] = c;                                                           \
        const float Ec  = __builtin_amdgcn_exp2f(fminf((2.f * LOG2E) * c, 120.f)); \
        hh[JJ] = (_Float16)((Ec - 1.f) *                                       \
                 __builtin_amdgcn_rcpf((1.f + eo) * (1.f + Ec)));              \
    }

#define STEP(J, P, GXC, GXN)                                                   \
    do {                                                                       \
        if (isL1 && (J) < T_STEPS) {                                           \
            /* issue h1(J-1) reads first */                                    \
            const half8 bf0 = *(const half8*)&Hb[P][ln][8 * lb];               \
            const half8 bf1 = *(const half8*)&Hb[P][ln][32 + 8 * lb];          \
            /* cover read latency: build gx(J+1) from registers */             \
            half8 xf;                                                          \
            _Pragma("unroll")                                                  \
            for (int j = 0; j < 4; ++j) { xf[j] = (_Float16)xr0[j]; xf[4+j] = (_Float16)xr1[j]; } \
            _Pragma("unroll")                                                  \
            for (int q = 0; q < 4; ++q) GXN[q] = bv[q];                        \
            _Pragma("unroll")                                                  \
            for (int q = 0; q < 4; ++q)                                        \
                GXN[q] = __builtin_amdgcn_mfma_f32_16x16x32_f16(wax[q], xf, GXN[q], 0, 0, 0); \
            /* prefetch x(J+2); vmcnt never drained at barrier */              \
            { const int jn = ((J) + 2 < T_STEPS) ? (J) + 2 : T_STEPS - 1;      \
              xr0 = *(const f32x4*)(xb + jn * 32);                             \
              xr1 = *(const f32x4*)(xb + jn * 32 + 4); }                       \
            /* layer 1 recurrent part */                                       \
            __builtin_amdgcn_s_setprio(1);                                     \
            _Pragma("unroll")                                                  \
            for (int q = 0; q < 4; ++q) {                                      \
                GXC[q] = __builtin_amdgcn_mfma_f32_16x16x32_f16(wa[q][0], bf0, GXC[q], 0, 0, 0); \
                GXC[q] = __builtin_amdgcn_mfma_f32_16x16x32_f16(wa[q][1], bf1, GXC[q], 0, 0, 0); \
            }                                                                  \
            __builtin_amdgcn_s_setprio(0);                                     \
            half4 hh;                                                          \
            ACT1(GXC, 0) ACT1(GXC, 1) ACT1(GXC, 2) ACT1(GXC, 3)                \
            *(half4*)&Hb[1 - (P)][ln][ub] = hh;                                \
        }                                                                      \
        if (!isL1 && (J) > 0) {                                                \
            const half8 bf0 = *(const half8*)&Hb[P][ln][8 * lb];               \
            const half8 bf1 = *(const half8*)&Hb[P][ln][32 + 8 * lb];          \
            const half8 bf2 = *(const half8*)&Hb[P][ln][64 + 8 * lb];          \
            const half8 bf3 = *(const half8*)&Hb[P][ln][96 + 8 * lb];          \
            f32x4 acc[4];                                                      \
            _Pragma("unroll")                                                  \
            for (int q = 0; q < 4; ++q) acc[q] = bv[q];                        \
            __builtin_amdgcn_s_setprio(1);                                     \
            _Pragma("unroll")                                                  \
            for (int q = 0; q < 4; ++q) {                                      \
                acc[q] = __builtin_amdgcn_mfma_f32_16x16x32_f16(wa[q][0], bf0, acc[q], 0, 0, 0); \
                acc[q] = __builtin_amdgcn_mfma_f32_16x16x32_f16(wa[q][1], bf1, acc[q], 0, 0, 0); \
                acc[q] = __builtin_amdgcn_mfma_f32_16x16x32_f16(wa[q][2], bf2, acc[q], 0, 0, 0); \
                acc[q] = __builtin_amdgcn_mfma_f32_16x16x32_f16(wa[q][3], bf3, acc[q], 0, 0, 0); \
            }                                                                  \
            __builtin_amdgcn_s_setprio(0);                                     \
            half4 hh;                                                          \
            ACT1(acc, 0) ACT1(acc, 1) ACT1(acc, 2) ACT1(acc, 3)                \
            *(half4*)&Hb[1 - (P)][ln][64 + ub] = hh;                           \
        }                                                                      \
        sync_lds();                                                            \
    } while (0)

    for (int jj = 0; jj < T_STEPS; jj += 2) {
        STEP(jj, 0, gxA, gxB);
        STEP(jj + 1, 1, gxB, gxA);
    }
    STEP(T_STEPS, 0, gxA, gxB);   // drain: layer 2 computes h2(255) -> Hb[1]

    // ---- output head: out[b] = h2(255) . Wout + bout ----
    if (tid < NB) {
        float s = bout[0];
        #pragma unroll
        for (int u8 = 0; u8 < 8; ++u8) {
            const half8 hv = *(const half8*)&Hb[1][tid][64 + 8 * u8];
            #pragma unroll
            for (int j = 0; j < 8; ++j)
                s += (float)hv[j] * Wout[8 * u8 + j];
        }
        out[gb0 + tid] = s;
    }
}

extern "C" void kernel_launch(void* const* d_in, const int* in_sizes, int n_in,
                              void* d_out, int out_size, void* d_ws, size_t ws_size,
                              hipStream_t stream) {
    const float* x    = (const float*)d_in[0];
    const float* Wih0 = (const float*)d_in[1];
    const float* Whh0 = (const float*)d_in[2];
    const float* bih0 = (const float*)d_in[3];
    const float* bhh0 = (const float*)d_in[4];
    const float* Wih1 = (const float*)d_in[5];
    const float* Whh1 = (const float*)d_in[6];
    const float* bih1 = (const float*)d_in[7];
    const float* bhh1 = (const float*)d_in[8];
    const float* Wout = (const float*)d_in[9];
    const float* bout = (const float*)d_in[10];

    hipLaunchKernelGGL(lstm_v6, dim3(NBLOCKS), dim3(512), 0, stream,
                       x, Wih0, Whh0, bih0, bhh0,
                       Wih1, Whh1, bih1, bhh1, Wout, bout,
                       (float*)d_out);
}

// Round 7
// 323.069 us; speedup vs baseline: 1.0485x; 1.0485x over previous
//
#include <hip/hip_runtime.h>

typedef _Float16 half8 __attribute__((ext_vector_type(8)));
typedef _Float16 half4 __attribute__((ext_vector_type(4)));
typedef float f32x4 __attribute__((ext_vector_type(4)));

#define T_STEPS 256
#define NB      8            // batches per block -> 512 blocks, target 2 blocks/CU
#define NBLOCKS (4096/NB)
#define LOG2E   1.4426950408889634f

// merged activation buffer stride (f16 units): cols 0..63 = h1, 64..127 = h2.
// 136 = 8*17 -> b128 reads conflict-free ((ln+lb)%8 chunk permutation),
// b64 writes uniform.
#define SH 136

__device__ __forceinline__ half8 cvt8s(const float* __restrict__ p, float s) {
    half8 r;
    #pragma unroll
    for (int j = 0; j < 8; ++j) r[j] = (_Float16)(p[j] * s);
    return r;
}

// LDS-only barrier: does NOT drain vmcnt, so global x prefetch stays in flight.
__device__ __forceinline__ void sync_lds() {
    asm volatile("s_waitcnt lgkmcnt(0)" ::: "memory");
    __builtin_amdgcn_s_barrier();
}

// __launch_bounds__(512, 4): min 4 waves/EU -> compiler caps VGPR+AGPR at 128,
// allowing TWO 8-wave blocks per CU (the round-6 failure was 168 regs -> 3/SIMD).
__global__ __launch_bounds__(512, 4)
void lstm_v7(const float* __restrict__ x,
             const float* __restrict__ Wih0, const float* __restrict__ Whh0,
             const float* __restrict__ bih0, const float* __restrict__ bhh0,
             const float* __restrict__ Wih1, const float* __restrict__ Whh1,
             const float* __restrict__ bih1, const float* __restrict__ bhh1,
             const float* __restrict__ Wout, const float* __restrict__ bout,
             float* __restrict__ out)
{
    __shared__ _Float16 Hb[2][16][SH];

    const int tid  = threadIdx.x;
    const int w    = tid >> 6;
    const bool isL1 = (w < 4);          // waves 0-3: layer 1; waves 4-7: layer 2
    const int wq   = w & 3;
    const int l    = tid & 63;
    const int ln   = l & 15;            // weight row (A) / batch col (B)
    const int lb   = l >> 4;            // k sub-block / C-row group
    const int ub   = 16 * wq + 4 * lb;  // first unit this lane's acc covers
    const int gb0  = blockIdx.x * NB;

    // ---- weight A-fragments, register-resident, sign/scale pre-folded ----
    // gate q scale: i,f,o -> -log2e (exp2(acc) = e^{-raw}); g -> +2*log2e.
    // L1: wa[q][0] = x-slice (K 0..31), wa[q][1..2] = h1-slices; [3] unused.
    // L2: wa[q][0..3] = [h1 | h2] K-slices.
    half8 wa[4][4];
    f32x4 bv[4];
    if (isL1) {
        #pragma unroll
        for (int q = 0; q < 4; ++q) {
            const float s = (q == 2) ? 2.f * LOG2E : -LOG2E;
            const int g = 64 * q + 16 * wq + ln;
            wa[q][0] = cvt8s(Wih0 + g * 32 + 8 * lb, s);
            #pragma unroll
            for (int ks = 0; ks < 2; ++ks)
                wa[q][1 + ks] = cvt8s(Whh0 + g * 64 + 32 * ks + 8 * lb, s);
            #pragma unroll
            for (int jj = 0; jj < 4; ++jj) {
                const int gj = 64 * q + ub + jj;
                bv[q][jj] = (bih0[gj] + bhh0[gj]) * s;
            }
        }
    } else {
        #pragma unroll
        for (int q = 0; q < 4; ++q) {
            const float s = (q == 2) ? 2.f * LOG2E : -LOG2E;
            const int g = 64 * q + 16 * wq + ln;
            #pragma unroll
            for (int ks = 0; ks < 4; ++ks) {
                const int c0 = 32 * ks + 8 * lb;
                const float* p = (c0 < 64) ? (Wih1 + g * 64 + c0)
                                           : (Whh1 + g * 64 + (c0 - 64));
                wa[q][ks] = cvt8s(p, s);
            }
            #pragma unroll
            for (int jj = 0; jj < 4; ++jj) {
                const int gj = 64 * q + ub + jj;
                bv[q][jj] = (bih1[gj] + bhh1[gj]) * s;
            }
        }
    }

    float cst[4] = {0.f, 0.f, 0.f, 0.f};

    // ---- zero LDS (h1(-1)=h2(-1)=h2(-2)=0) ----
    {
        unsigned int* z = (unsigned int*)Hb;
        for (int i = tid; i < (int)(sizeof(Hb) / 4); i += 512) z[i] = 0u;
    }

    // ---- L1 x path: lane owns x[batch gb0+(ln&7)][t][8lb..8lb+7]
    //      (ln 8..15 duplicate 0..7 -> no OOB; loads coalesce/L1-hit) ----
    const float* xb = x + (long)(gb0 + (ln & (NB - 1))) * T_STEPS * 32 + 8 * lb;
    f32x4 xr0 = {0.f,0.f,0.f,0.f}, xr1 = {0.f,0.f,0.f,0.f};
    if (isL1) {
        xr0 = *(const f32x4*)(xb);       // x(0)
        xr1 = *(const f32x4*)(xb + 4);
    }
    sync_lds();

// LSTM cell update, weights pre-scaled: ei=e^{-i}, ef=e^{-f}, Eg=e^{2g}, eo=e^{-o}
// c' = [c*(1+ei)(1+Eg) + (Eg-1)(1+ef)] / ((1+ei)(1+Eg)(1+ef))
// h  = (Ec-1) / ((1+eo)(1+Ec)),  Ec = e^{2c'}
#define ACT1(A, JJ)                                                            \
    {                                                                          \
        const float ei = __builtin_amdgcn_exp2f(A[0][JJ]);                     \
        const float ef = __builtin_amdgcn_exp2f(A[1][JJ]);                     \
        const float Eg = __builtin_amdgcn_exp2f(A[2][JJ]);                     \
        const float eo = __builtin_amdgcn_exp2f(A[3][JJ]);                     \
        const float ti = 1.f + ei, tf = 1.f + ef, tg = 1.f + Eg;               \
        const float pig = ti * tg;                                             \
        const float num = fmaf(Eg - 1.f, tf, cst[JJ] * pig);                   \
        const float c   = num * __builtin_amdgcn_rcpf(pig * tf);               \
        cst[JJ] = c;                                                           \
        const float Ec  = __builtin_amdgcn_exp2f(fminf((2.f * LOG2E) * c, 120.f)); \
        hh[JJ] = (_Float16)((Ec - 1.f) *                                       \
                 __builtin_amdgcn_rcpf((1.f + eo) * (1.f + Ec)));              \
    }

#define STEP(J, P)                                                             \
    do {                                                                       \
        if (isL1 && (J) < T_STEPS) {                                           \
            /* issue h1(J-1) reads first (ds latency covered by x-MFMAs) */    \
            const half8 bf0 = *(const half8*)&Hb[P][ln][8 * lb];               \
            const half8 bf1 = *(const half8*)&Hb[P][ln][32 + 8 * lb];          \
            /* consume x(J) from regs, then immediately prefetch x(J+1) */     \
            half8 xf;                                                          \
            _Pragma("unroll")                                                  \
            for (int j = 0; j < 4; ++j) { xf[j] = (_Float16)xr0[j]; xf[4+j] = (_Float16)xr1[j]; } \
            if ((J) + 1 < T_STEPS) {                                           \
                xr0 = *(const f32x4*)(xb + ((J) + 1) * 32);                    \
                xr1 = *(const f32x4*)(xb + ((J) + 1) * 32 + 4);                \
            }                                                                  \
            f32x4 acc[4];                                                      \
            _Pragma("unroll")                                                  \
            for (int q = 0; q < 4; ++q)                                        \
                acc[q] = __builtin_amdgcn_mfma_f32_16x16x32_f16(wa[q][0], xf, bv[q], 0, 0, 0); \
            __builtin_amdgcn_s_setprio(1);                                     \
            _Pragma("unroll")                                                  \
            for (int q = 0; q < 4; ++q) {                                      \
                acc[q] = __builtin_amdgcn_mfma_f32_16x16x32_f16(wa[q][1], bf0, acc[q], 0, 0, 0); \
                acc[q] = __builtin_amdgcn_mfma_f32_16x16x32_f16(wa[q][2], bf1, acc[q], 0, 0, 0); \
            }                                                                  \
            __builtin_amdgcn_s_setprio(0);                                     \
            half4 hh;                                                          \
            ACT1(acc, 0) ACT1(acc, 1) ACT1(acc, 2) ACT1(acc, 3)                \
            *(half4*)&Hb[1 - (P)][ln][ub] = hh;                                \
        }                                                                      \
        if (!isL1 && (J) > 0) {                                                \
            const half8 bf0 = *(const half8*)&Hb[P][ln][8 * lb];               \
            const half8 bf1 = *(const half8*)&Hb[P][ln][32 + 8 * lb];          \
            const half8 bf2 = *(const half8*)&Hb[P][ln][64 + 8 * lb];          \
            const half8 bf3 = *(const half8*)&Hb[P][ln][96 + 8 * lb];          \
            f32x4 acc[4];                                                      \
            __builtin_amdgcn_s_setprio(1);                                     \
            _Pragma("unroll")                                                  \
            for (int q = 0; q < 4; ++q) {                                      \
                acc[q] = __builtin_amdgcn_mfma_f32_16x16x32_f16(wa[q][0], bf0, bv[q], 0, 0, 0); \
                acc[q] = __builtin_amdgcn_mfma_f32_16x16x32_f16(wa[q][1], bf1, acc[q], 0, 0, 0); \
                acc[q] = __builtin_amdgcn_mfma_f32_16x16x32_f16(wa[q][2], bf2, acc[q], 0, 0, 0); \
                acc[q] = __builtin_amdgcn_mfma_f32_16x16x32_f16(wa[q][3], bf3, acc[q], 0, 0, 0); \
            }                                                                  \
            __builtin_amdgcn_s_setprio(0);                                     \
            half4 hh;                                                          \
            ACT1(acc, 0) ACT1(acc, 1) ACT1(acc, 2) ACT1(acc, 3)                \
            *(half4*)&Hb[1 - (P)][ln][64 + ub] = hh;                           \
        }                                                                      \
        sync_lds();                                                            \
    } while (0)

    for (int jj = 0; jj < T_STEPS; jj += 2) {
        STEP(jj, 0);
        STEP(jj + 1, 1);
    }
    STEP(T_STEPS, 0);   // drain: layer 2 computes h2(255) -> Hb[1]

    // ---- output head: out[b] = h2(255) . Wout + bout ----
    if (tid < NB) {
        float s = bout[0];
        #pragma unroll
        for (int u8 = 0; u8 < 8; ++u8) {
            const half8 hv = *(const half8*)&Hb[1][tid][64 + 8 * u8];
            #pragma unroll
            for (int j = 0; j < 8; ++j)
                s += (float)hv[j] * Wout[8 * u8 + j];
        }
        out[gb0 + tid] = s;
    }
}

extern "C" void kernel_launch(void* const* d_in, const int* in_sizes, int n_in,
                              void* d_out, int out_size, void* d_ws, size_t ws_size,
                              hipStream_t stream) {
    const float* x    = (const float*)d_in[0];
    const float* Wih0 = (const float*)d_in[1];
    const float* Whh0 = (const float*)d_in[2];
    const float* bih0 = (const float*)d_in[3];
    const float* bhh0 = (const float*)d_in[4];
    const float* Wih1 = (const float*)d_in[5];
    const float* Whh1 = (const float*)d_in[6];
    const float* bih1 = (const float*)d_in[7];
    const float* bhh1 = (const float*)d_in[8];
    const float* Wout = (const float*)d_in[9];
    const float* bout = (const float*)d_in[10];

    hipLaunchKernelGGL(lstm_v7, dim3(NBLOCKS), dim3(512), 0, stream,
                       x, Wih0, Whh0, bih0, bhh0,
                       Wih1, Whh1, bih1, bhh1, Wout, bout,
                       (float*)d_out);
}